// Round 4
// baseline (374.786 us; speedup 1.0000x reference)
//
#include <hip/hip_runtime.h>
#include <hip/hip_cooperative_groups.h>

namespace cg = cooperative_groups;

// PositionalSparseLinear2d: out[b,o] = sum_k input[b, conn[o,k]] * weights[o,k]
// B=64, N_in = N_out = 512*512 = 262144, K=8, fp32 in/out.
// x_t is stored BF16 (threshold 7.3e-2; bf16 absmax measured 0.0156): row =
// 64*2B = 128 B = one fetch granule.
//
// R8: single COOPERATIVE kernel = transpose phase + grid.sync + gather phase.
//  * Rationale: residual (dur_us - gather) was a constant ~115 us across
//    R0/R1/R3 but transpose never shows in top-5 (<64 us) -> can't split
//    transpose vs harness overhead. One dispatch makes total compute time
//    directly visible; also deletes one launch gap.
//  * NT out stores REVERTED (R3: WRITE_SIZE 66->118 MB partial-line
//    amplification, +14 us). Plain stores; L2 merges partials.
//  * NT input loads kept (zero-reuse 67 MB stream; measured neutral).
//  * Transpose readout: one row per thread per pass -> each wave store is
//    1 KB CONTIGUOUS (was 8 x 128 B stride-256). Costs a 4-way LDS read
//    conflict (~1.6x on a ~3 us pipe) -- acceptable.

#define IN_N  (512*512)
#define OUT_N (512*512)
#define BATCH 64
#define KCONN 8
#define TIDX  128   // idx-columns per transpose tile
#define NTILE (IN_N / TIDX)   // 2048 transpose tiles
#define NOT   (OUT_N / 32)    // 8192 gather tiles

typedef float f32x4 __attribute__((ext_vector_type(4)));

__device__ inline unsigned f2bf(float f) {                  // RNE fp32->bf16
    unsigned u; __builtin_memcpy(&u, &f, 4);
    return (u + 0x7fffu + ((u >> 16) & 1u)) >> 16;
}
__device__ inline float bflo(unsigned u) {                  // low bf16 -> fp32
    unsigned v = u << 16; float f; __builtin_memcpy(&f, &v, 4); return f;
}
__device__ inline float bfhi(unsigned u) {                  // high bf16 -> fp32
    unsigned v = u & 0xffff0000u; float f; __builtin_memcpy(&f, &v, 4); return f;
}

// ---------------------------------------------------------------------------
// Fused cooperative kernel.
// Phase 1 (transpose): grid-stride over 2048 tiles of 128 idx-columns.
//   Load: NT float4, coalesced. Convert fp32->bf16 pre-LDS, pack idx-pairs,
//   8 B LDS stores (2-way banks, free). LDS = 64 x 65 uints = 16.6 KB.
//   Readout: thread -> one full 128 B row; wave -> 8 consecutive rows = 1 KB
//   contiguous store per instruction.
// Phase 2 (gather): grid-stride over 8192 o-tiles (32 outputs each).
//   8-lane group per o: per k all 8 lanes read ONE x_t row contiguously.
//   Lane accumulates its own 8 batches across k in registers; plain stores.
// ---------------------------------------------------------------------------
__global__ __launch_bounds__(256, 8) void fused_kernel(const float* __restrict__ in,
                                                       unsigned short* __restrict__ xt,
                                                       const int* __restrict__ conn,
                                                       const float* __restrict__ w,
                                                       float* __restrict__ out) {
    __shared__ unsigned lds_u[BATCH][TIDX / 2 + 1];   // 64 x 65 x 4 B = 16.6 KB
    const int t = threadIdx.x;

    // ---------------- phase 1: transpose + downconvert ----------------
    for (int tile = blockIdx.x; tile < NTILE; tile += gridDim.x) {
        const int idx0 = tile * TIDX;
        const int lb = t >> 5;          // 0..7
        const int lc = (t & 31) << 2;   // 0,4,...,124
#pragma unroll
        for (int p = 0; p < 8; ++p) {
            const int b = p * 8 + lb;
            f32x4 v = __builtin_nontemporal_load(
                (const f32x4*)(in + (size_t)b * IN_N + idx0 + lc));
            lds_u[b][(lc >> 1) + 0] = f2bf(v.x) | (f2bf(v.y) << 16);
            lds_u[b][(lc >> 1) + 1] = f2bf(v.z) | (f2bf(v.w) << 16);
        }
        __syncthreads();

        const int rl = t >> 3;          // 0..31: row-local within pass
        const int sb = (t & 7) << 3;    // batch start: 0,8,...,56
#pragma unroll
        for (int p = 0; p < 4; ++p) {
            const int i = p * 32 + rl;          // row 0..127 in tile
            const int c = i >> 1;               // packed column
            const int h = i & 1;                // which half of the pair
            union { unsigned short s[8]; uint4 v4; } pk;
#pragma unroll
            for (int e = 0; e < 8; ++e) {
                const unsigned u = lds_u[sb + e][c];
                pk.s[e] = (unsigned short)(h ? (u >> 16) : (u & 0xffffu));
            }
            *(uint4*)(xt + (size_t)(idx0 + i) * BATCH + sb) = pk.v4;
        }
        __syncthreads();   // LDS reused by next tile iteration
    }

    // make x_t visible device-wide, then grid barrier
    __threadfence();
    cg::this_grid().sync();

    // ---------------- phase 2: gather ----------------
    const int ol = t >> 3;                   // 0..31
    const int ch = t & 7;                    // batch chunk: batches ch*8..ch*8+7
    for (int tile = blockIdx.x; tile < NOT; tile += gridDim.x) {
        const int o = tile * 32 + ol;

        const int4   c0 = ((const int4*)conn)[(size_t)o * 2 + 0];
        const int4   c1 = ((const int4*)conn)[(size_t)o * 2 + 1];
        const float4 w0 = ((const float4*)w)[(size_t)o * 2 + 0];
        const float4 w1 = ((const float4*)w)[(size_t)o * 2 + 1];
        const int   cidx[KCONN] = {c0.x, c0.y, c0.z, c0.w, c1.x, c1.y, c1.z, c1.w};
        const float wk[KCONN]   = {w0.x, w0.y, w0.z, w0.w, w1.x, w1.y, w1.z, w1.w};

        float acc[8] = {0.f, 0.f, 0.f, 0.f, 0.f, 0.f, 0.f, 0.f};
#pragma unroll
        for (int k = 0; k < KCONN; ++k) {
            const uint4 r = *(const uint4*)(xt + (size_t)cidx[k] * BATCH + ch * 8);
            const unsigned q[4] = {r.x, r.y, r.z, r.w};
            const float wv = wk[k];
#pragma unroll
            for (int e = 0; e < 4; ++e) {
                acc[2 * e + 0] += bflo(q[e]) * wv;
                acc[2 * e + 1] += bfhi(q[e]) * wv;
            }
        }
#pragma unroll
        for (int j = 0; j < 8; ++j) {
            out[(size_t)(ch * 8 + j) * OUT_N + o] = acc[j];
        }
    }
}

// ---------------------------------------------------------------------------
// Fallback (workspace too small for the 33.5 MiB bf16 copy).
// ---------------------------------------------------------------------------
__global__ __launch_bounds__(256) void direct_kernel(const float* __restrict__ in,
                                                     const int* __restrict__ conn,
                                                     const float* __restrict__ w,
                                                     float* __restrict__ out) {
    const int o = blockIdx.x * 256 + threadIdx.x;

    const int4   c0 = ((const int4*)conn)[(size_t)o * 2 + 0];
    const int4   c1 = ((const int4*)conn)[(size_t)o * 2 + 1];
    const float4 w0 = ((const float4*)w)[(size_t)o * 2 + 0];
    const float4 w1 = ((const float4*)w)[(size_t)o * 2 + 1];

    const int   cidx[KCONN] = {c0.x, c0.y, c0.z, c0.w, c1.x, c1.y, c1.z, c1.w};
    const float wk[KCONN]   = {w0.x, w0.y, w0.z, w0.w, w1.x, w1.y, w1.z, w1.w};

    for (int b = 0; b < BATCH; ++b) {
        const float* xb = in + (size_t)b * IN_N;
        float acc = 0.0f;
#pragma unroll
        for (int k = 0; k < KCONN; ++k) acc += xb[cidx[k]] * wk[k];
        out[(size_t)b * OUT_N + o] = acc;
    }
}

extern "C" void kernel_launch(void* const* d_in, const int* in_sizes, int n_in,
                              void* d_out, int out_size, void* d_ws, size_t ws_size,
                              hipStream_t stream) {
    const float* inp  = (const float*)d_in[0];   // (64, 512, 512) fp32
    const int*   conn = (const int*)d_in[1];     // (262144, 8) int32
    const float* w    = (const float*)d_in[2];   // (262144, 8) fp32
    float*       out  = (float*)d_out;           // (64, 262144) fp32

    const size_t xt_bytes = (size_t)IN_N * BATCH * sizeof(unsigned short);  // 33.5 MiB

    // Cached cooperative-capacity query (pure host queries; graph-safe).
    static int coop_grid = -2;   // -2 = not queried, -1 = unavailable
    if (coop_grid == -2) {
        int blocksPerCU = 0, numCU = 0;
        hipError_t e1 = hipOccupancyMaxActiveBlocksPerMultiprocessor(
            &blocksPerCU, (const void*)fused_kernel, 256, 0);
        hipError_t e2 = hipDeviceGetAttribute(
            &numCU, hipDeviceAttributeMultiprocessorCount, 0);
        if (e1 == hipSuccess && e2 == hipSuccess && blocksPerCU > 0 && numCU > 0) {
            int g = blocksPerCU * numCU;
            coop_grid = g < NTILE ? g : NTILE;   // cap at 2048 (= #transpose tiles)
        } else {
            coop_grid = -1;
        }
    }

    if (ws_size >= xt_bytes && coop_grid > 0) {
        unsigned short* xt = (unsigned short*)d_ws;
        void* args[] = {(void*)&inp, (void*)&xt, (void*)&conn, (void*)&w, (void*)&out};
        hipLaunchCooperativeKernel((const void*)fused_kernel,
                                   dim3(coop_grid), dim3(256), args, 0, stream);
    } else {
        direct_kernel<<<OUT_N / 256, 256, 0, stream>>>(inp, conn, w, out);
    }
}

// Round 5
// 170.138 us; speedup vs baseline: 2.2028x; 2.2028x over previous
//
#include <hip/hip_runtime.h>

// PositionalSparseLinear2d: out[b,o] = sum_k input[b, conn[o,k]] * weights[o,k]
// B=64, N_in = N_out = 512*512 = 262144, K=8, fp32 in/out.
// x_t is stored BF16 (threshold 7.3e-2; measured bf16 absmax 0.0156): row =
// 64*2B = 128 B = one fetch granule.
//
// R9 = R1 (best recorded: 178.7 us) + two mechanistic fixes:
//  * R4 cooperative fusion REVERTED (uniform 3.7x latency stretch: VALU 3%,
//    HBM 8%, occupancy 94% -- grid-stride + grid.sync serialization loses to
//    block-churn pipelining).
//  * gather: explicit r[0..7] prefetch. R1's 20-VGPR rolled k-loop
//    serialized 8 x ~500cy x_t load latencies per thread (VALUBusy 14%,
//    BW 38% = exposed latency, not fabric ceiling). All 8 independent loads
//    now issue back-to-back before first use; waitcnt drains progressively.
//  * transpose: NT input loads (67 MB zero-reuse stream; measured safe in R3).
//    NT out stores stay dead (R3: partial-line amplification WRITE 66->118 MB).

#define IN_N  (512*512)
#define OUT_N (512*512)
#define BATCH 64
#define KCONN 8
#define TIDX  128   // idx-columns per transpose tile

typedef float f32x4 __attribute__((ext_vector_type(4)));

__device__ inline unsigned f2bf(float f) {                  // RNE fp32->bf16
    unsigned u; __builtin_memcpy(&u, &f, 4);
    return (u + 0x7fffu + ((u >> 16) & 1u)) >> 16;
}
__device__ inline float bflo(unsigned u) {                  // low bf16 -> fp32
    unsigned v = u << 16; float f; __builtin_memcpy(&f, &v, 4); return f;
}
__device__ inline float bfhi(unsigned u) {                  // high bf16 -> fp32
    unsigned v = u & 0xffff0000u; float f; __builtin_memcpy(&f, &v, 4); return f;
}

// ---------------------------------------------------------------------------
// Kernel 1: transpose+downconvert input (BATCH, IN_N) fp32 -> x_t (IN_N,
// BATCH) bf16. 128-idx x 64-batch tile, 256 threads.
// Load: NT float4, coalesced. Convert fp32->bf16 pre-LDS, pack idx-pairs,
// 8 B LDS stores. LDS = 64 x 65 uints = 16.6 KB -> 8 blocks/CU.
// Readout (R1 layout): per wave-instruction the store is 1 KB contiguous
// (8 consecutive rows x 128 B); LDS read banks 2-way (free).
// ---------------------------------------------------------------------------
__global__ __launch_bounds__(256, 8) void transpose_kernel(const float* __restrict__ in,
                                                           unsigned short* __restrict__ xt) {
    __shared__ unsigned lds_u[BATCH][TIDX / 2 + 1];   // 64 x 65 x 4 B = 16.6 KB
    const int t    = threadIdx.x;
    const int idx0 = blockIdx.x * TIDX;

    const int lb = t >> 5;          // 0..7
    const int lc = (t & 31) << 2;   // 0,4,...,124
#pragma unroll
    for (int p = 0; p < 8; ++p) {
        const int b = p * 8 + lb;
        f32x4 v = __builtin_nontemporal_load(
            (const f32x4*)(in + (size_t)b * IN_N + idx0 + lc));
        lds_u[b][(lc >> 1) + 0] = f2bf(v.x) | (f2bf(v.y) << 16);
        lds_u[b][(lc >> 1) + 1] = f2bf(v.z) | (f2bf(v.w) << 16);
    }
    __syncthreads();

    const int si = t >> 3;          // 0..31 (uint column within pass)
    const int sb = (t & 7) << 3;    // batch start: 0,8,...,56
#pragma unroll
    for (int p = 0; p < 2; ++p) {
        const int col = p * 32 + si;        // packed column = idx pair {2col, 2col+1}
        unsigned lo[4], hi[4];
#pragma unroll
        for (int j = 0; j < 4; ++j) {
            const unsigned a  = lds_u[sb + 2 * j + 0][col];
            const unsigned b2 = lds_u[sb + 2 * j + 1][col];
            lo[j] = (a & 0xffffu) | (b2 << 16);          // idx 2col,   batches sb+2j, sb+2j+1
            hi[j] = (a >> 16) | (b2 & 0xffff0000u);      // idx 2col+1, batches sb+2j, sb+2j+1
        }
        union { unsigned u[4]; uint4 v; } pk;
        pk.u[0] = lo[0]; pk.u[1] = lo[1]; pk.u[2] = lo[2]; pk.u[3] = lo[3];
        *(uint4*)(xt + (size_t)(idx0 + 2 * col + 0) * BATCH + sb) = pk.v;
        pk.u[0] = hi[0]; pk.u[1] = hi[1]; pk.u[2] = hi[2]; pk.u[3] = hi[3];
        *(uint4*)(xt + (size_t)(idx0 + 2 * col + 1) * BATCH + sb) = pk.v;
    }
}

// ---------------------------------------------------------------------------
// Kernel 2: gather on bf16 x_t. Lane = (o_local = t>>3, chunk = t&7).
// Per k, the 8 lanes of an o-group read ONE row contiguously. All 8 x_t
// loads are prefetched into r[0..7] BEFORE any use: one exposed x_t latency
// per thread instead of eight. conn/w int4/float4 loads issue in parallel.
// ---------------------------------------------------------------------------
__global__ __launch_bounds__(256, 8) void gather_kernel(const unsigned short* __restrict__ xt,
                                                        const int* __restrict__ conn,
                                                        const float* __restrict__ w,
                                                        float* __restrict__ out) {
    const int t  = threadIdx.x;
    const int o0 = blockIdx.x * 32;          // 32 outputs per block
    const int ol = t >> 3;                   // 0..31
    const int ch = t & 7;                    // batch chunk: batches ch*8..ch*8+7
    const int o  = o0 + ol;

    // All 8 lanes of a group load the same conn/w rows (same-address merge).
    const int4   c0 = ((const int4*)conn)[(size_t)o * 2 + 0];
    const int4   c1 = ((const int4*)conn)[(size_t)o * 2 + 1];
    const float4 w0 = ((const float4*)w)[(size_t)o * 2 + 0];
    const float4 w1 = ((const float4*)w)[(size_t)o * 2 + 1];
    const int   cidx[KCONN] = {c0.x, c0.y, c0.z, c0.w, c1.x, c1.y, c1.z, c1.w};
    const float wk[KCONN]   = {w0.x, w0.y, w0.z, w0.w, w1.x, w1.y, w1.z, w1.w};

    // Prefetch: 8 independent 16 B loads, all in flight simultaneously.
    uint4 r[KCONN];
#pragma unroll
    for (int k = 0; k < KCONN; ++k) {
        r[k] = *(const uint4*)(xt + (size_t)cidx[k] * BATCH + ch * 8);
    }

    float acc[8] = {0.f, 0.f, 0.f, 0.f, 0.f, 0.f, 0.f, 0.f};
#pragma unroll
    for (int k = 0; k < KCONN; ++k) {
        const unsigned q[4] = {r[k].x, r[k].y, r[k].z, r[k].w};
        const float wv = wk[k];
#pragma unroll
        for (int e = 0; e < 4; ++e) {
            acc[2 * e + 0] += bflo(q[e]) * wv;
            acc[2 * e + 1] += bfhi(q[e]) * wv;
        }
    }

#pragma unroll
    for (int j = 0; j < 8; ++j) {
        out[(size_t)(ch * 8 + j) * OUT_N + o] = acc[j];
    }
}

// ---------------------------------------------------------------------------
// Fallback (only if workspace is too small for the 33.5 MiB bf16 copy).
// ---------------------------------------------------------------------------
__global__ __launch_bounds__(256) void direct_kernel(const float* __restrict__ in,
                                                     const int* __restrict__ conn,
                                                     const float* __restrict__ w,
                                                     float* __restrict__ out) {
    const int o = blockIdx.x * 256 + threadIdx.x;

    const int4   c0 = ((const int4*)conn)[(size_t)o * 2 + 0];
    const int4   c1 = ((const int4*)conn)[(size_t)o * 2 + 1];
    const float4 w0 = ((const float4*)w)[(size_t)o * 2 + 0];
    const float4 w1 = ((const float4*)w)[(size_t)o * 2 + 1];

    const int   cidx[KCONN] = {c0.x, c0.y, c0.z, c0.w, c1.x, c1.y, c1.z, c1.w};
    const float wk[KCONN]   = {w0.x, w0.y, w0.z, w0.w, w1.x, w1.y, w1.z, w1.w};

    for (int b = 0; b < BATCH; ++b) {
        const float* xb = in + (size_t)b * IN_N;
        float acc = 0.0f;
#pragma unroll
        for (int k = 0; k < KCONN; ++k) acc += xb[cidx[k]] * wk[k];
        out[(size_t)b * OUT_N + o] = acc;
    }
}

extern "C" void kernel_launch(void* const* d_in, const int* in_sizes, int n_in,
                              void* d_out, int out_size, void* d_ws, size_t ws_size,
                              hipStream_t stream) {
    const float* inp  = (const float*)d_in[0];   // (64, 512, 512) fp32
    const int*   conn = (const int*)d_in[1];     // (262144, 8) int32
    const float* w    = (const float*)d_in[2];   // (262144, 8) fp32
    float*       out  = (float*)d_out;           // (64, 262144) fp32

    const size_t xt_bytes = (size_t)IN_N * BATCH * sizeof(unsigned short);  // 33.5 MiB

    if (ws_size >= xt_bytes) {
        unsigned short* xt = (unsigned short*)d_ws;
        transpose_kernel<<<IN_N / TIDX, 256, 0, stream>>>(inp, xt);
        gather_kernel<<<OUT_N / 32, 256, 0, stream>>>(xt, conn, w, out);
    } else {
        direct_kernel<<<OUT_N / 256, 256, 0, stream>>>(inp, conn, w, out);
    }
}